// Round 5
// baseline (391.880 us; speedup 1.0000x reference)
//
#include <hip/hip_runtime.h>
#include <cstdint>
#include <cstddef>

using short8 = short __attribute__((ext_vector_type(8)));   // 8 bf16 = 4 VGPRs
using f32x4  = float __attribute__((ext_vector_type(4)));   // MFMA accumulator

__device__ __forceinline__ unsigned short f2bf(float f) {
  unsigned int u = __float_as_uint(f);
  u += 0x7fffu + ((u >> 16) & 1u);            // round-to-nearest-even
  return (unsigned short)(u >> 16);
}
__device__ __forceinline__ float bf2f(unsigned short s) {
  return __uint_as_float(((unsigned int)s) << 16);
}
// pack two f32 -> two bf16 (round-half-up) in one v_perm_b32
__device__ __forceinline__ unsigned int pack_bf16_rhu(float lo, float hi) {
  unsigned int a = __float_as_uint(lo) + 0x8000u;
  unsigned int b = __float_as_uint(hi) + 0x8000u;
  return __builtin_amdgcn_perm(b, a, 0x07060302u);  // {a.b2,a.b3,b.b2,b.b3}
}
__device__ __forceinline__ void async16(const void* g, void* l) {
  __builtin_amdgcn_global_load_lds(
      (const __attribute__((address_space(1))) unsigned int*)g,
      (__attribute__((address_space(3))) unsigned int*)l, 16, 0, 0);
}

#define D_MODEL 1024
#define NHEAD   16
#define HEADD   64
#define SEQL    2048
#define NTOK    4096
// 0.125 (1/sqrt(64)) * log2(e): folded into Q so softmax uses v_exp_f32 directly
#define QSCALE  0.18033688011112042f

// ---------------------------------------------------------------------------
// fp32 -> bf16 cast
// ---------------------------------------------------------------------------
__global__ __launch_bounds__(256) void cvt_f32_bf16(const float* __restrict__ in,
                                                    unsigned short* __restrict__ out,
                                                    int n4) {
  int i = blockIdx.x * 256 + threadIdx.x;
  if (i >= n4) return;
  float4 v = ((const float4*)in)[i];
  union { unsigned long long u; unsigned int ui[2]; } pk;
  pk.ui[0] = pack_bf16_rhu(v.x, v.y);
  pk.ui[1] = pack_bf16_rhu(v.z, v.w);
  ((unsigned long long*)out)[i] = pk.u;
}

// ---------------------------------------------------------------------------
// all 6 weight transposes ([R][C] f32 -> [C][R] bf16) in ONE launch
// ---------------------------------------------------------------------------
struct TransTab {
  const float* src[6];
  unsigned short* dst[6];
  int R[6], C[6], start[6], shift[6];
};

__global__ __launch_bounds__(256) void transpose_all(TransTab tt) {
  int id = blockIdx.x, m = 0;
#pragma unroll
  for (int i = 1; i < 6; ++i) if (id >= tt.start[i]) m = i;
  const int local = id - tt.start[m];
  const int R = tt.R[m], C = tt.C[m];
  const int bc = (local & ((1 << tt.shift[m]) - 1)) * 32;
  const int br = (local >> tt.shift[m]) * 32;
  const float* in = tt.src[m];
  unsigned short* out = tt.dst[m];
  __shared__ float tile[32][33];
  const int tx = threadIdx.x & 31, ty = threadIdx.x >> 5;
#pragma unroll
  for (int i = 0; i < 32; i += 8)
    tile[ty + i][tx] = in[(size_t)(br + ty + i) * C + bc + tx];
  __syncthreads();
#pragma unroll
  for (int i = 0; i < 32; i += 8)
    out[(size_t)(bc + ty + i) * R + br + tx] = f2bf(tile[tx][ty + i]);
}

// ---------------------------------------------------------------------------
// GEMM: C[M][N] = A[M][K-slice] @ B^T, B stored [N][Kstride].
// blockIdx.z selects K-slice. 128x128 tile, BK=64, 4 waves.
// MODE 0: QKV  (+bias, scatter Q*QSCALE / K / V^T)
// MODE 1: PARTIAL (raw fp32 -> outF + z*M*N)
// MODE 2: FFN1 (+bias, tanh-approx GELU -> bf16)
// ---------------------------------------------------------------------------
template <int MODE>
__global__ __launch_bounds__(256, 4)
void gemm_bt(const unsigned short* __restrict__ A, const unsigned short* __restrict__ B,
             int M, int N, int K, int Kstride,
             const float* __restrict__ bias0, const float* __restrict__ bias1,
             const float* __restrict__ bias2,
             float* __restrict__ outF, unsigned short* __restrict__ outB,
             unsigned short* __restrict__ outQ, unsigned short* __restrict__ outK,
             unsigned short* __restrict__ outVT) {
  __shared__ __align__(16) short sA[128 * 64];   // 16 KB
  __shared__ __align__(16) short sB[128 * 64];   // 16 KB
  const int tid = threadIdx.x, wave = tid >> 6, lane = tid & 63;
  const int quad = lane >> 4, l16 = lane & 15;
  const int bm = blockIdx.y * 128, bn = blockIdx.x * 128;
  const int koff = blockIdx.z * K;
  const int wr = (wave >> 1) * 64, wc = (wave & 1) * 64;
  const f32x4 zero4 = {0.f, 0.f, 0.f, 0.f};
  f32x4 acc[4][4];
#pragma unroll
  for (int i = 0; i < 4; ++i)
#pragma unroll
    for (int j = 0; j < 4; ++j) acc[i][j] = zero4;

  for (int kt = 0; kt < K; kt += 64) {
    __syncthreads();
#pragma unroll
    for (int j = 0; j < 4; ++j) {
      int c = (wave * 4 + j) * 64 + lane;       // chunk 0..1023
      int row = c >> 3, cp = c & 7;
      int gk = koff + kt + ((cp ^ (row & 7)) * 8);
      async16(A + (size_t)(bm + row) * Kstride + gk, &sA[(wave * 4 + j) * 512]);
      async16(B + (size_t)(bn + row) * Kstride + gk, &sB[(wave * 4 + j) * 512]);
    }
    __syncthreads();
#pragma unroll
    for (int kk = 0; kk < 2; ++kk) {            // two 32-k half-steps
      short8 af[4], bfr[4];
#pragma unroll
      for (int i = 0; i < 4; ++i) {
        int ra = wr + i * 16 + l16;
        af[i] = *(const short8*)&sA[ra * 64 + (((kk * 4 + quad) ^ (ra & 7)) * 8)];
        int rb = wc + i * 16 + l16;
        bfr[i] = *(const short8*)&sB[rb * 64 + (((kk * 4 + quad) ^ (rb & 7)) * 8)];
      }
#pragma unroll
      for (int mi = 0; mi < 4; ++mi)
#pragma unroll
        for (int ni = 0; ni < 4; ++ni)
          acc[mi][ni] = __builtin_amdgcn_mfma_f32_16x16x32_bf16(af[mi], bfr[ni], acc[mi][ni], 0, 0, 0);
    }
  }

#pragma unroll
  for (int mi = 0; mi < 4; ++mi)
#pragma unroll
    for (int ni = 0; ni < 4; ++ni) {
      const int col = bn + wc + ni * 16 + l16;
      const int row0 = bm + wr + mi * 16 + quad * 4;
      if constexpr (MODE == 0) {
        const int b_ = row0 >> 11, l_ = row0 & 2047;   // 4 rows never straddle batch
        if (col < 1024) {
          const int hh = col >> 6, dd = col & 63;
          const size_t o = (((size_t)(b_ * NHEAD + hh)) * SEQL + l_) * HEADD + dd;
#pragma unroll
          for (int r = 0; r < 4; ++r)
            outQ[o + (size_t)r * HEADD] = f2bf((acc[mi][ni][r] + bias0[col]) * QSCALE);
        } else if (col < 2048) {
          const int n2 = col - 1024, hh = n2 >> 6, dd = n2 & 63;
          const size_t o = (((size_t)(b_ * NHEAD + hh)) * SEQL + l_) * HEADD + dd;
#pragma unroll
          for (int r = 0; r < 4; ++r)
            outK[o + (size_t)r * HEADD] = f2bf(acc[mi][ni][r] + bias1[n2]);
        } else {
          const int n2 = col - 2048, hh = n2 >> 6, dd = n2 & 63;
          union { unsigned long long u; unsigned short us[4]; } pk;
#pragma unroll
          for (int r = 0; r < 4; ++r) pk.us[r] = f2bf(acc[mi][ni][r] + bias2[n2]);
          *(unsigned long long*)&outVT[(((size_t)(b_ * NHEAD + hh)) * HEADD + dd) * SEQL + l_] = pk.u;
        }
      } else if constexpr (MODE == 1) {
        float* o = outF + (size_t)blockIdx.z * M * N + (size_t)row0 * N + col;
#pragma unroll
        for (int r = 0; r < 4; ++r) o[(size_t)r * N] = acc[mi][ni][r];
      } else {
#pragma unroll
        for (int r = 0; r < 4; ++r) {
          float x = acc[mi][ni][r] + bias0[col];
          float x2 = x * x;
          float z = x * fmaf(0.102944f, x2, 2.302208f);
          float t = __builtin_amdgcn_exp2f(z);
          float gl = x - x * __builtin_amdgcn_rcpf(t + 1.0f);
          outB[(size_t)(row0 + r) * N + col] = f2bf(gl);
        }
      }
    }
}

// ---------------------------------------------------------------------------
// Flash attention, transposed-S, 256 threads (4 waves x 32 q = 2 q-tiles).
// K and Q fragments are contiguous 16B runs in global memory -> loaded
// DIRECTLY from global (no sK, no K/Q staging barriers). Only V^T is staged
// in LDS (B-operand needs the transpose); P round-trips wave-private sP with
// b64 writes. LDS = sV 16KB + sP 18KB = 34 KB. Each V/K fragment feeds 2
// MFMAs (mi reuse) -> ~2.3x fewer LDS bytes per MFMA than round-4.
// ---------------------------------------------------------------------------
__global__ __launch_bounds__(256)
void flash_attn(const unsigned short* __restrict__ Qb, const unsigned short* __restrict__ Kb,
                const unsigned short* __restrict__ VTb, unsigned short* __restrict__ attnA) {
  __shared__ __align__(16) short sV[64 * 128];   // [d][kv] swizzled
  __shared__ __align__(16) short sP[128 * 72];   // [q][64 kv + pad]
  const int tid = threadIdx.x, wave = tid >> 6, lane = tid & 63;
  const int quad = lane >> 4, l16 = lane & 15;
  const int bh = blockIdx.y;
  const int q0 = blockIdx.x * 128;
  const size_t baseQK = (size_t)bh * SEQL * HEADD;
  const size_t baseV  = (size_t)bh * HEADD * SEQL;

  // Q B-fragments direct from global: B[k=d][n=q], lane n=q, k-chunk quad*8
  short8 qf[2][2];
#pragma unroll
  for (int mi = 0; mi < 2; ++mi)
#pragma unroll
    for (int kk = 0; kk < 2; ++kk) {
      int q = q0 + wave * 32 + mi * 16 + l16;
      qf[mi][kk] = *(const short8*)(Qb + baseQK + (size_t)q * HEADD + kk * 32 + quad * 8);
    }

  const f32x4 zero4 = {0.f, 0.f, 0.f, 0.f};
  f32x4 o_acc[2][4];                 // [mi][d-tile]; row=q(quad*4+r), col=d(l16)
  float lsum[2] = {0.f, 0.f};        // sum-exp for q = wave*32+mi*16+l16
#pragma unroll
  for (int mi = 0; mi < 2; ++mi)
#pragma unroll
    for (int ni = 0; ni < 4; ++ni) o_acc[mi][ni] = zero4;

  for (int t0 = 0; t0 < SEQL; t0 += 128) {
    __syncthreads();               // prev tile's sV reads done
#pragma unroll
    for (int j = 0; j < 4; ++j) {
      int c = (wave * 4 + j) * 64 + lane;        // 16B chunks of the V tile
      int d = c >> 4, cp = c & 15;
      int gl = (cp ^ (d & 15)) * 8;
      async16(VTb + baseV + (size_t)d * SEQL + t0 + gl, &sV[(wave * 4 + j) * 512]);
    }
    __syncthreads();

#pragma unroll
    for (int h = 0; h < 2; ++h) {            // 64-kv halves
      // ---- S^T[kv][q]: A = K rows direct from global, B = Q regs ----
      f32x4 st[4][2];
#pragma unroll
      for (int kt = 0; kt < 4; ++kt)
#pragma unroll
        for (int mi = 0; mi < 2; ++mi) st[kt][mi] = zero4;
#pragma unroll
      for (int kt = 0; kt < 4; ++kt) {
        const unsigned short* kp =
            Kb + baseQK + (size_t)(t0 + h * 64 + kt * 16 + l16) * HEADD + quad * 8;
        short8 a0 = *(const short8*)(kp);
        short8 a1 = *(const short8*)(kp + 32);
#pragma unroll
        for (int mi = 0; mi < 2; ++mi) {
          st[kt][mi] = __builtin_amdgcn_mfma_f32_16x16x32_bf16(a0, qf[mi][0], st[kt][mi], 0, 0, 0);
          st[kt][mi] = __builtin_amdgcn_mfma_f32_16x16x32_bf16(a1, qf[mi][1], st[kt][mi], 0, 0, 0);
        }
      }
      // ---- exp2 (scale pre-folded), denom, packed b64 P writes ----
#pragma unroll
      for (int kt = 0; kt < 4; ++kt)
#pragma unroll
        for (int mi = 0; mi < 2; ++mi) {
          float e0 = __builtin_amdgcn_exp2f(st[kt][mi][0]);
          float e1 = __builtin_amdgcn_exp2f(st[kt][mi][1]);
          float e2 = __builtin_amdgcn_exp2f(st[kt][mi][2]);
          float e3 = __builtin_amdgcn_exp2f(st[kt][mi][3]);
          lsum[mi] += (e0 + e1) + (e2 + e3);
          int q = wave * 32 + mi * 16 + l16;
          union { unsigned long long u; unsigned int ui[2]; } pk;
          pk.ui[0] = pack_bf16_rhu(e0, e1);
          pk.ui[1] = pack_bf16_rhu(e2, e3);
          *(unsigned long long*)&sP[q * 72 + kt * 16 + quad * 4] = pk.u;
        }
      // ---- O += P V (sP rows wave-private; same-wave LDS ops ordered) ----
#pragma unroll
      for (int c = 0; c < 2; ++c) {
        short8 pf[2];
#pragma unroll
        for (int mi = 0; mi < 2; ++mi) {
          int q = wave * 32 + mi * 16 + l16;
          pf[mi] = *(const short8*)&sP[q * 72 + c * 32 + quad * 8];
        }
#pragma unroll
        for (int ni = 0; ni < 4; ++ni) {
          int vrow = ni * 16 + l16;
          short8 vf = *(const short8*)&sV[vrow * 128 + (((h * 8 + c * 4 + quad) ^ (vrow & 15)) * 8)];
#pragma unroll
          for (int mi = 0; mi < 2; ++mi)
            o_acc[mi][ni] = __builtin_amdgcn_mfma_f32_16x16x32_bf16(pf[mi], vf, o_acc[mi][ni], 0, 0, 0);
        }
      }
    }
  }

  // reduce denominators across quads (same l16 = same q), then write O/l
#pragma unroll
  for (int mi = 0; mi < 2; ++mi) {
    lsum[mi] += __shfl_xor(lsum[mi], 16, 64);
    lsum[mi] += __shfl_xor(lsum[mi], 32, 64);
  }
  const int b_ = bh >> 4, hh = bh & 15;
#pragma unroll
  for (int mi = 0; mi < 2; ++mi)
#pragma unroll
    for (int r = 0; r < 4; ++r) {
      float inv = 1.0f / __shfl(lsum[mi], quad * 4 + r, 64);
      int qrow = q0 + wave * 32 + mi * 16 + quad * 4 + r;
      size_t orow = ((size_t)(b_ * SEQL + qrow)) * D_MODEL + hh * HEADD;
#pragma unroll
      for (int ni = 0; ni < 4; ++ni)
        attnA[orow + ni * 16 + l16] = f2bf(o_acc[mi][ni][r] * inv);
    }
}

// ---------------------------------------------------------------------------
// LN combine: sum nsplit fp32 partial slices (+bias +residual), LayerNorm.
// ---------------------------------------------------------------------------
__device__ __forceinline__ void ln_core(float x0, float x1, float x2, float x3,
                                        const float* gamma, const float* beta,
                                        int tid, float& y0, float& y1, float& y2, float& y3) {
  float s = x0 + x1 + x2 + x3;
  float q = x0 * x0 + x1 * x1 + x2 * x2 + x3 * x3;
#pragma unroll
  for (int m = 1; m < 64; m <<= 1) {
    s += __shfl_xor(s, m, 64);
    q += __shfl_xor(q, m, 64);
  }
  __shared__ float red[8];
  const int wv = tid >> 6, ln = tid & 63;
  if (ln == 0) { red[wv] = s; red[4 + wv] = q; }
  __syncthreads();
  float S = red[0] + red[1] + red[2] + red[3];
  float Q2 = red[4] + red[5] + red[6] + red[7];
  float mu = S * (1.0f / 1024.0f);
  float var = Q2 * (1.0f / 1024.0f) - mu * mu;
  float rstd = rsqrtf(var + 1e-5f);
  float4 g = ((const float4*)gamma)[tid];
  float4 b = ((const float4*)beta)[tid];
  y0 = (x0 - mu) * rstd * g.x + b.x;
  y1 = (x1 - mu) * rstd * g.y + b.y;
  y2 = (x2 - mu) * rstd * g.z + b.z;
  y3 = (x3 - mu) * rstd * g.w + b.w;
}

__global__ __launch_bounds__(256)
void ln_combine1(const float* __restrict__ p, int nsplit, const float* __restrict__ src,
                 const float* __restrict__ bias, const float* __restrict__ gamma,
                 const float* __restrict__ beta, unsigned short* __restrict__ outB) {
  const int t = blockIdx.x, tid = threadIdx.x;
  const size_t MN = (size_t)NTOK * 1024, base = (size_t)t * 1024;
  float4 a = ((const float4*)(p + base))[tid];
  for (int s = 1; s < nsplit; ++s) {
    float4 b4 = ((const float4*)(p + s * MN + base))[tid];
    a.x += b4.x; a.y += b4.y; a.z += b4.z; a.w += b4.w;
  }
  float4 s4 = ((const float4*)(src + base))[tid];
  float4 bi = ((const float4*)bias)[tid];
  float y0, y1, y2, y3;
  ln_core(a.x + s4.x + bi.x, a.y + s4.y + bi.y,
          a.z + s4.z + bi.z, a.w + s4.w + bi.w,
          gamma, beta, tid, y0, y1, y2, y3);
  union { unsigned long long u; unsigned int ui[2]; } pk;
  pk.ui[0] = (unsigned)f2bf(y0) | ((unsigned)f2bf(y1) << 16);
  pk.ui[1] = (unsigned)f2bf(y2) | ((unsigned)f2bf(y3) << 16);
  ((unsigned long long*)(outB + base))[tid] = pk.u;
}

__global__ __launch_bounds__(256)
void ln_combine2(const float* __restrict__ p, int nsplit, const unsigned short* __restrict__ resB,
                 const float* __restrict__ bias, const float* __restrict__ gamma,
                 const float* __restrict__ beta, float* __restrict__ outF) {
  const int t = blockIdx.x, tid = threadIdx.x;
  const size_t MN = (size_t)NTOK * 1024, base = (size_t)t * 1024;
  float4 a = ((const float4*)(p + base))[tid];
  for (int s = 1; s < nsplit; ++s) {
    float4 b4 = ((const float4*)(p + s * MN + base))[tid];
    a.x += b4.x; a.y += b4.y; a.z += b4.z; a.w += b4.w;
  }
  union { unsigned long long u; unsigned short us[4]; } r;
  r.u = ((const unsigned long long*)(resB + base))[tid];
  float4 bi = ((const float4*)bias)[tid];
  float y0, y1, y2, y3;
  ln_core(a.x + bf2f(r.us[0]) + bi.x, a.y + bf2f(r.us[1]) + bi.y,
          a.z + bf2f(r.us[2]) + bi.z, a.w + bf2f(r.us[3]) + bi.w,
          gamma, beta, tid, y0, y1, y2, y3);
  float4 o = {y0, y1, y2, y3};
  ((float4*)(outF + base))[tid] = o;
}

// ---------------------------------------------------------------------------
extern "C" void kernel_launch(void* const* d_in, const int* in_sizes, int n_in,
                              void* d_out, int out_size, void* d_ws, size_t ws_size,
                              hipStream_t stream) {
  const float* src    = (const float*)d_in[0];
  const float* Wq     = (const float*)d_in[1];
  const float* bq     = (const float*)d_in[2];
  const float* Wk     = (const float*)d_in[3];
  const float* bk     = (const float*)d_in[4];
  const float* Wv     = (const float*)d_in[5];
  const float* bv     = (const float*)d_in[6];
  const float* Wo     = (const float*)d_in[7];
  const float* bo     = (const float*)d_in[8];
  const float* W1     = (const float*)d_in[9];
  const float* b1     = (const float*)d_in[10];
  const float* W2     = (const float*)d_in[11];
  const float* b2     = (const float*)d_in[12];
  const float* gamma1 = (const float*)d_in[13];
  const float* beta1  = (const float*)d_in[14];
  const float* gamma2 = (const float*)d_in[15];
  const float* beta2  = (const float*)d_in[16];
  float* out = (float*)d_out;
  (void)in_sizes; (void)n_in; (void)out_size;

  char* p = (char*)d_ws;
  size_t used = 0;
  auto carve = [&](size_t n) {
    char* r = p; size_t a = (n + 255) & ~(size_t)255; p += a; used += a; return r;
  };
  unsigned short* srcB  = (unsigned short*)carve((size_t)NTOK * 1024 * 2);   // + attnA reuse
  unsigned short* WqkvT = (unsigned short*)carve((size_t)3072 * 1024 * 2);
  unsigned short* WoT   = (unsigned short*)carve((size_t)1024 * 1024 * 2);
  unsigned short* W1T   = (unsigned short*)carve((size_t)4096 * 1024 * 2);
  unsigned short* W2T   = (unsigned short*)carve((size_t)1024 * 4096 * 2);
  unsigned short* Qb    = (unsigned short*)carve((size_t)NTOK * 1024 * 2);   // \ partial
  unsigned short* Kb    = (unsigned short*)carve((size_t)NTOK * 1024 * 2);   // |  (32MB,
  unsigned short* VTb   = (unsigned short*)carve((size_t)NTOK * 1024 * 2);   // |  2 slices)
  carve((size_t)NTOK * 1024 * 2);                                            // /
  unsigned short* xln   = (unsigned short*)carve((size_t)NTOK * 1024 * 2);
  unsigned short* hmid  = (unsigned short*)carve((size_t)NTOK * 4096 * 2);
  unsigned short* attnA = srcB;             // srcB dead after QKV GEMM
  float* partial2 = (float*)Qb;             // Qb..spare dead after flash (32 MB)
  // dedicated 4-slice partial region if workspace allows
  const size_t need4 = (size_t)NTOK * 1024 * 4 * 4;
  float* partial4 = (ws_size >= used + need4) ? (float*)carve(need4) : nullptr;
  const int nsplit = partial4 ? 4 : 2;
  float* partial = partial4 ? partial4 : partial2;

  // pre-pass
  cvt_f32_bf16<<<4096, 256, 0, stream>>>(src, srcB, NTOK * 1024 / 4);
  TransTab tt;
  tt.src[0] = Wq; tt.src[1] = Wk; tt.src[2] = Wv; tt.src[3] = Wo; tt.src[4] = W1; tt.src[5] = W2;
  tt.dst[0] = WqkvT; tt.dst[1] = WqkvT + 1024 * 1024; tt.dst[2] = WqkvT + 2 * 1024 * 1024;
  tt.dst[3] = WoT; tt.dst[4] = W1T; tt.dst[5] = W2T;
  for (int i = 0; i < 4; ++i) { tt.R[i] = 1024; tt.C[i] = 1024; tt.shift[i] = 5; }
  tt.R[4] = 1024; tt.C[4] = 4096; tt.shift[4] = 7;
  tt.R[5] = 4096; tt.C[5] = 1024; tt.shift[5] = 5;
  tt.start[0] = 0; tt.start[1] = 1024; tt.start[2] = 2048; tt.start[3] = 3072;
  tt.start[4] = 4096; tt.start[5] = 8192;
  transpose_all<<<12288, 256, 0, stream>>>(tt);

  // QKV projection -> Q(scaled)/K/VT
  gemm_bt<0><<<dim3(24, 32, 1), 256, 0, stream>>>(srcB, WqkvT, NTOK, 3072, 1024, 1024,
                                                  bq, bk, bv, nullptr, nullptr, Qb, Kb, VTb);
  // attention (256 threads, 4 waves, direct-global K/Q)
  flash_attn<<<dim3(16, 32), 256, 0, stream>>>(Qb, Kb, VTb, attnA);
  // O-projection, split-K -> fp32 partials
  gemm_bt<1><<<dim3(8, 32, nsplit), 256, 0, stream>>>(attnA, WoT, NTOK, 1024, 1024 / nsplit, 1024,
                                                      nullptr, nullptr, nullptr, partial,
                                                      nullptr, nullptr, nullptr, nullptr);
  // LN1 (partials + bo + src residual) -> bf16
  ln_combine1<<<NTOK, 256, 0, stream>>>(partial, nsplit, src, bo, gamma1, beta1, xln);
  // FFN1 + GELU -> bf16
  gemm_bt<2><<<dim3(32, 32, 1), 256, 0, stream>>>(xln, W1T, NTOK, 4096, 1024, 1024,
                                                  b1, nullptr, nullptr, nullptr, hmid,
                                                  nullptr, nullptr, nullptr);
  // FFN2, split-K -> fp32 partials
  gemm_bt<1><<<dim3(8, 32, nsplit), 256, 0, stream>>>(hmid, W2T, NTOK, 1024, 4096 / nsplit, 4096,
                                                      nullptr, nullptr, nullptr, partial,
                                                      nullptr, nullptr, nullptr, nullptr);
  // LN2 (partials + b2 + xln residual) -> f32 out
  ln_combine2<<<NTOK, 256, 0, stream>>>(partial, nsplit, xln, b2, gamma2, beta2, out);
}

// Round 6
// 354.634 us; speedup vs baseline: 1.1050x; 1.1050x over previous
//
#include <hip/hip_runtime.h>
#include <cstdint>
#include <cstddef>

using short8 = short __attribute__((ext_vector_type(8)));   // 8 bf16 = 4 VGPRs
using f32x4  = float __attribute__((ext_vector_type(4)));   // MFMA accumulator

__device__ __forceinline__ unsigned short f2bf(float f) {
  unsigned int u = __float_as_uint(f);
  u += 0x7fffu + ((u >> 16) & 1u);            // round-to-nearest-even
  return (unsigned short)(u >> 16);
}
__device__ __forceinline__ float bf2f(unsigned short s) {
  return __uint_as_float(((unsigned int)s) << 16);
}
// pack two f32 -> two bf16 (round-half-up) in one v_perm_b32
__device__ __forceinline__ unsigned int pack_bf16_rhu(float lo, float hi) {
  unsigned int a = __float_as_uint(lo) + 0x8000u;
  unsigned int b = __float_as_uint(hi) + 0x8000u;
  return __builtin_amdgcn_perm(b, a, 0x07060302u);  // {a.b2,a.b3,b.b2,b.b3}
}
__device__ __forceinline__ void async16(const void* g, void* l) {
  __builtin_amdgcn_global_load_lds(
      (const __attribute__((address_space(1))) unsigned int*)g,
      (__attribute__((address_space(3))) unsigned int*)l, 16, 0, 0);
}

#define D_MODEL 1024
#define NHEAD   16
#define HEADD   64
#define SEQL    2048
#define NTOK    4096
// 0.125 (1/sqrt(64)) * log2(e): folded into Q so softmax uses v_exp_f32 directly
#define QSCALE  0.18033688011112042f

// ---------------------------------------------------------------------------
// prep: blocks [0,4096) cast src f32->bf16; blocks [4096,16384) transpose the
// 6 weight matrices ([R][C] f32 -> [C][R] bf16). One launch total.
// ---------------------------------------------------------------------------
struct TransTab {
  const float* src[6];
  unsigned short* dst[6];
  int R[6], C[6], start[6], shift[6];
  const float* cvt_in;
  unsigned short* cvt_out;
};

__global__ __launch_bounds__(256) void prep_all(TransTab tt) {
  __shared__ float tile[32][33];
  int id = blockIdx.x;
  if (id < 4096) {               // cast path: 4096 blocks x 256 thr x 1 float4
    int i = id * 256 + threadIdx.x;
    float4 v = ((const float4*)tt.cvt_in)[i];
    union { unsigned long long u; unsigned int ui[2]; } pk;
    pk.ui[0] = pack_bf16_rhu(v.x, v.y);
    pk.ui[1] = pack_bf16_rhu(v.z, v.w);
    ((unsigned long long*)tt.cvt_out)[i] = pk.u;
    return;
  }
  id -= 4096;
  int m = 0;
#pragma unroll
  for (int i = 1; i < 6; ++i) if (id >= tt.start[i]) m = i;
  const int local = id - tt.start[m];
  const int R = tt.R[m], C = tt.C[m];
  const int bc = (local & ((1 << tt.shift[m]) - 1)) * 32;
  const int br = (local >> tt.shift[m]) * 32;
  const float* in = tt.src[m];
  unsigned short* out = tt.dst[m];
  const int tx = threadIdx.x & 31, ty = threadIdx.x >> 5;
#pragma unroll
  for (int i = 0; i < 32; i += 8)
    tile[ty + i][tx] = in[(size_t)(br + ty + i) * C + bc + tx];
  __syncthreads();
#pragma unroll
  for (int i = 0; i < 32; i += 8)
    out[(size_t)(bc + ty + i) * R + br + tx] = f2bf(tile[tx][ty + i]);
}

// ---------------------------------------------------------------------------
// GEMM: C[M][N] = A[M][K-slice] @ B^T, B stored [N][Kstride].
// blockIdx.z selects K-slice. 128x128 tile, BK=64, 4 waves.
// MODE 0: QKV  (+bias, scatter Q*QSCALE / K / V^T)
// MODE 1: PARTIAL (raw fp32 -> outF + z*M*N)
// MODE 2: FFN1 (+bias, tanh-approx GELU -> bf16)
// ---------------------------------------------------------------------------
template <int MODE>
__global__ __launch_bounds__(256, 4)
void gemm_bt(const unsigned short* __restrict__ A, const unsigned short* __restrict__ B,
             int M, int N, int K, int Kstride,
             const float* __restrict__ bias0, const float* __restrict__ bias1,
             const float* __restrict__ bias2,
             float* __restrict__ outF, unsigned short* __restrict__ outB,
             unsigned short* __restrict__ outQ, unsigned short* __restrict__ outK,
             unsigned short* __restrict__ outVT) {
  __shared__ __align__(16) short sA[128 * 64];   // 16 KB
  __shared__ __align__(16) short sB[128 * 64];   // 16 KB
  const int tid = threadIdx.x, wave = tid >> 6, lane = tid & 63;
  const int quad = lane >> 4, l16 = lane & 15;
  const int bm = blockIdx.y * 128, bn = blockIdx.x * 128;
  const int koff = blockIdx.z * K;
  const int wr = (wave >> 1) * 64, wc = (wave & 1) * 64;
  const f32x4 zero4 = {0.f, 0.f, 0.f, 0.f};
  f32x4 acc[4][4];
#pragma unroll
  for (int i = 0; i < 4; ++i)
#pragma unroll
    for (int j = 0; j < 4; ++j) acc[i][j] = zero4;

  for (int kt = 0; kt < K; kt += 64) {
    __syncthreads();
#pragma unroll
    for (int j = 0; j < 4; ++j) {
      int c = (wave * 4 + j) * 64 + lane;       // chunk 0..1023
      int row = c >> 3, cp = c & 7;
      int gk = koff + kt + ((cp ^ (row & 7)) * 8);
      async16(A + (size_t)(bm + row) * Kstride + gk, &sA[(wave * 4 + j) * 512]);
      async16(B + (size_t)(bn + row) * Kstride + gk, &sB[(wave * 4 + j) * 512]);
    }
    __syncthreads();
#pragma unroll
    for (int kk = 0; kk < 2; ++kk) {            // two 32-k half-steps
      short8 af[4], bfr[4];
#pragma unroll
      for (int i = 0; i < 4; ++i) {
        int ra = wr + i * 16 + l16;
        af[i] = *(const short8*)&sA[ra * 64 + (((kk * 4 + quad) ^ (ra & 7)) * 8)];
        int rb = wc + i * 16 + l16;
        bfr[i] = *(const short8*)&sB[rb * 64 + (((kk * 4 + quad) ^ (rb & 7)) * 8)];
      }
#pragma unroll
      for (int mi = 0; mi < 4; ++mi)
#pragma unroll
        for (int ni = 0; ni < 4; ++ni)
          acc[mi][ni] = __builtin_amdgcn_mfma_f32_16x16x32_bf16(af[mi], bfr[ni], acc[mi][ni], 0, 0, 0);
    }
  }

#pragma unroll
  for (int mi = 0; mi < 4; ++mi)
#pragma unroll
    for (int ni = 0; ni < 4; ++ni) {
      const int col = bn + wc + ni * 16 + l16;
      const int row0 = bm + wr + mi * 16 + quad * 4;
      if constexpr (MODE == 0) {
        const int b_ = row0 >> 11, l_ = row0 & 2047;   // 4 rows never straddle batch
        if (col < 1024) {
          const int hh = col >> 6, dd = col & 63;
          const size_t o = (((size_t)(b_ * NHEAD + hh)) * SEQL + l_) * HEADD + dd;
#pragma unroll
          for (int r = 0; r < 4; ++r)
            outQ[o + (size_t)r * HEADD] = f2bf((acc[mi][ni][r] + bias0[col]) * QSCALE);
        } else if (col < 2048) {
          const int n2 = col - 1024, hh = n2 >> 6, dd = n2 & 63;
          const size_t o = (((size_t)(b_ * NHEAD + hh)) * SEQL + l_) * HEADD + dd;
#pragma unroll
          for (int r = 0; r < 4; ++r)
            outK[o + (size_t)r * HEADD] = f2bf(acc[mi][ni][r] + bias1[n2]);
        } else {
          const int n2 = col - 2048, hh = n2 >> 6, dd = n2 & 63;
          union { unsigned long long u; unsigned short us[4]; } pk;
#pragma unroll
          for (int r = 0; r < 4; ++r) pk.us[r] = f2bf(acc[mi][ni][r] + bias2[n2]);
          *(unsigned long long*)&outVT[(((size_t)(b_ * NHEAD + hh)) * HEADD + dd) * SEQL + l_] = pk.u;
        }
      } else if constexpr (MODE == 1) {
        float* o = outF + (size_t)blockIdx.z * M * N + (size_t)row0 * N + col;
#pragma unroll
        for (int r = 0; r < 4; ++r) o[(size_t)r * N] = acc[mi][ni][r];
      } else {
#pragma unroll
        for (int r = 0; r < 4; ++r) {
          float x = acc[mi][ni][r] + bias0[col];
          float x2 = x * x;
          float z = x * fmaf(0.102944f, x2, 2.302208f);
          float t = __builtin_amdgcn_exp2f(z);
          float gl = x - x * __builtin_amdgcn_rcpf(t + 1.0f);
          outB[(size_t)(row0 + r) * N + col] = f2bf(gl);
        }
      }
    }
}

// ---------------------------------------------------------------------------
// Flash attention (round-4 proven version): transposed-S, 512 threads
// (8 waves x 16 q rows). Block = 128 q x all kv. S^T = K.Q^T -> P lands q on
// lane&15, kv on quad*4+r: packed b32 LDS writes, direct A-fragment reads.
// No max-subtraction (scores bounded; softmax shift-invariant); per-lane
// denominator. LDS ~50KB -> 2 blocks/CU (grid 512) = 16 waves/CU.
// ---------------------------------------------------------------------------
__global__ __launch_bounds__(512)
void flash_attn(const unsigned short* __restrict__ Qb, const unsigned short* __restrict__ Kb,
                const unsigned short* __restrict__ VTb, unsigned short* __restrict__ attnA) {
  __shared__ __align__(16) short sK[128 * 64];   // [kv][d] swizzled (Q staging first)
  __shared__ __align__(16) short sV[64 * 128];   // [d][kv] swizzled
  __shared__ __align__(16) short sP[128 * 72];   // [q][kv-half 64 + pad 8]
  const int tid = threadIdx.x, wave = tid >> 6, lane = tid & 63;
  const int quad = lane >> 4, l16 = lane & 15;
  const int bh = blockIdx.y;
  const int q0 = blockIdx.x * 128;
  const size_t baseQK = (size_t)bh * SEQL * HEADD;
  const size_t baseV  = (size_t)bh * HEADD * SEQL;

  // stage Q tile (128x64) into sK, lift B-fragments to registers
#pragma unroll
  for (int j = 0; j < 2; ++j) {
    int c = (wave * 2 + j) * 64 + lane;
    int row = c >> 3, cp = c & 7;
    int gk = (cp ^ (row & 7)) * 8;
    async16(Qb + baseQK + (size_t)(q0 + row) * HEADD + gk, &sK[(wave * 2 + j) * 512]);
  }
  __syncthreads();
  short8 qf[2];
  {
    int m = wave * 16 + l16;
#pragma unroll
    for (int kk = 0; kk < 2; ++kk)
      qf[kk] = *(const short8*)&sK[m * 64 + (((kk * 4 + quad) ^ (m & 7)) * 8)];
  }

  const f32x4 zero4 = {0.f, 0.f, 0.f, 0.f};
  f32x4 o_acc[4];                  // [d-tile]; row=q(quad*4+r), col=d(l16)
  float lsum = 0.f;                // sum-exp partial for q = wave*16+l16
#pragma unroll
  for (int ni = 0; ni < 4; ++ni) o_acc[ni] = zero4;

  for (int t0 = 0; t0 < SEQL; t0 += 128) {
    __syncthreads();               // all reads of sK/sV (or Q-frags) done
#pragma unroll
    for (int j = 0; j < 2; ++j) {
      int c = (wave * 2 + j) * 64 + lane;
      { int row = c >> 3, cp = c & 7;
        int gk = (cp ^ (row & 7)) * 8;
        async16(Kb + baseQK + (size_t)(t0 + row) * HEADD + gk, &sK[(wave * 2 + j) * 512]); }
      { int d = c >> 4, cp = c & 15;
        int gl = (cp ^ (d & 15)) * 8;
        async16(VTb + baseV + (size_t)d * SEQL + t0 + gl, &sV[(wave * 2 + j) * 512]); }
    }
    __syncthreads();

    const int q = wave * 16 + l16;
#pragma unroll
    for (int h = 0; h < 2; ++h) {            // 64-kv halves
      // ---- S^T[kv][q]: A = K rows, B = Q regs ----
      f32x4 st[4];
#pragma unroll
      for (int kt = 0; kt < 4; ++kt) st[kt] = zero4;
#pragma unroll
      for (int kt = 0; kt < 4; ++kt) {
        int krow = (h * 4 + kt) * 16 + l16;
        short8 a0 = *(const short8*)&sK[krow * 64 + ((quad ^ (krow & 7)) * 8)];
        short8 a1 = *(const short8*)&sK[krow * 64 + (((4 + quad) ^ (krow & 7)) * 8)];
        st[kt] = __builtin_amdgcn_mfma_f32_16x16x32_bf16(a0, qf[0], st[kt], 0, 0, 0);
        st[kt] = __builtin_amdgcn_mfma_f32_16x16x32_bf16(a1, qf[1], st[kt], 0, 0, 0);
      }
      // ---- exp2 (scale pre-folded), accumulate denom, packed P writes ----
#pragma unroll
      for (int kt = 0; kt < 4; ++kt) {
        float e0 = __builtin_amdgcn_exp2f(st[kt][0]);
        float e1 = __builtin_amdgcn_exp2f(st[kt][1]);
        float e2 = __builtin_amdgcn_exp2f(st[kt][2]);
        float e3 = __builtin_amdgcn_exp2f(st[kt][3]);
        lsum += (e0 + e1) + (e2 + e3);
        unsigned int* bp = (unsigned int*)&sP[q * 72 + kt * 16 + quad * 4];
        bp[0] = pack_bf16_rhu(e0, e1);
        bp[1] = pack_bf16_rhu(e2, e3);
      }
      // ---- O += P V (sP rows wave-private; same-wave LDS ops ordered) ----
#pragma unroll
      for (int c = 0; c < 2; ++c) {
        short8 pf = *(const short8*)&sP[q * 72 + c * 32 + quad * 8];
#pragma unroll
        for (int ni = 0; ni < 4; ++ni) {
          int vrow = ni * 16 + l16;
          short8 vf = *(const short8*)&sV[vrow * 128 + (((h * 8 + c * 4 + quad) ^ (vrow & 15)) * 8)];
          o_acc[ni] = __builtin_amdgcn_mfma_f32_16x16x32_bf16(pf, vf, o_acc[ni], 0, 0, 0);
        }
      }
    }
  }

  // reduce denominator across quads (same l16 = same q), then write O/l
  lsum += __shfl_xor(lsum, 16, 64);
  lsum += __shfl_xor(lsum, 32, 64);
  const int b_ = bh >> 4, hh = bh & 15;
#pragma unroll
  for (int r = 0; r < 4; ++r) {
    float inv = 1.0f / __shfl(lsum, quad * 4 + r, 64);
    int qrow = q0 + wave * 16 + quad * 4 + r;
    size_t orow = ((size_t)(b_ * SEQL + qrow)) * D_MODEL + hh * HEADD;
#pragma unroll
    for (int ni = 0; ni < 4; ++ni)
      attnA[orow + ni * 16 + l16] = f2bf(o_acc[ni][r] * inv);
  }
}

// ---------------------------------------------------------------------------
// LN combine: sum nsplit fp32 partial slices (+bias +residual), LayerNorm.
// ---------------------------------------------------------------------------
__device__ __forceinline__ void ln_core(float x0, float x1, float x2, float x3,
                                        const float* gamma, const float* beta,
                                        int tid, float& y0, float& y1, float& y2, float& y3) {
  float s = x0 + x1 + x2 + x3;
  float q = x0 * x0 + x1 * x1 + x2 * x2 + x3 * x3;
#pragma unroll
  for (int m = 1; m < 64; m <<= 1) {
    s += __shfl_xor(s, m, 64);
    q += __shfl_xor(q, m, 64);
  }
  __shared__ float red[8];
  const int wv = tid >> 6, ln = tid & 63;
  if (ln == 0) { red[wv] = s; red[4 + wv] = q; }
  __syncthreads();
  float S = red[0] + red[1] + red[2] + red[3];
  float Q2 = red[4] + red[5] + red[6] + red[7];
  float mu = S * (1.0f / 1024.0f);
  float var = Q2 * (1.0f / 1024.0f) - mu * mu;
  float rstd = rsqrtf(var + 1e-5f);
  float4 g = ((const float4*)gamma)[tid];
  float4 b = ((const float4*)beta)[tid];
  y0 = (x0 - mu) * rstd * g.x + b.x;
  y1 = (x1 - mu) * rstd * g.y + b.y;
  y2 = (x2 - mu) * rstd * g.z + b.z;
  y3 = (x3 - mu) * rstd * g.w + b.w;
}

__global__ __launch_bounds__(256)
void ln_combine1(const float* __restrict__ p, int nsplit, const float* __restrict__ src,
                 const float* __restrict__ bias, const float* __restrict__ gamma,
                 const float* __restrict__ beta, unsigned short* __restrict__ outB) {
  const int t = blockIdx.x, tid = threadIdx.x;
  const size_t MN = (size_t)NTOK * 1024, base = (size_t)t * 1024;
  float4 a = ((const float4*)(p + base))[tid];
  for (int s = 1; s < nsplit; ++s) {
    float4 b4 = ((const float4*)(p + s * MN + base))[tid];
    a.x += b4.x; a.y += b4.y; a.z += b4.z; a.w += b4.w;
  }
  float4 s4 = ((const float4*)(src + base))[tid];
  float4 bi = ((const float4*)bias)[tid];
  float y0, y1, y2, y3;
  ln_core(a.x + s4.x + bi.x, a.y + s4.y + bi.y,
          a.z + s4.z + bi.z, a.w + s4.w + bi.w,
          gamma, beta, tid, y0, y1, y2, y3);
  union { unsigned long long u; unsigned int ui[2]; } pk;
  pk.ui[0] = (unsigned)f2bf(y0) | ((unsigned)f2bf(y1) << 16);
  pk.ui[1] = (unsigned)f2bf(y2) | ((unsigned)f2bf(y3) << 16);
  ((unsigned long long*)(outB + base))[tid] = pk.u;
}

__global__ __launch_bounds__(256)
void ln_combine2(const float* __restrict__ p, int nsplit, const unsigned short* __restrict__ resB,
                 const float* __restrict__ bias, const float* __restrict__ gamma,
                 const float* __restrict__ beta, float* __restrict__ outF) {
  const int t = blockIdx.x, tid = threadIdx.x;
  const size_t MN = (size_t)NTOK * 1024, base = (size_t)t * 1024;
  float4 a = ((const float4*)(p + base))[tid];
  for (int s = 1; s < nsplit; ++s) {
    float4 b4 = ((const float4*)(p + s * MN + base))[tid];
    a.x += b4.x; a.y += b4.y; a.z += b4.z; a.w += b4.w;
  }
  union { unsigned long long u; unsigned short us[4]; } r;
  r.u = ((const unsigned long long*)(resB + base))[tid];
  float4 bi = ((const float4*)bias)[tid];
  float y0, y1, y2, y3;
  ln_core(a.x + bf2f(r.us[0]) + bi.x, a.y + bf2f(r.us[1]) + bi.y,
          a.z + bf2f(r.us[2]) + bi.z, a.w + bf2f(r.us[3]) + bi.w,
          gamma, beta, tid, y0, y1, y2, y3);
  float4 o = {y0, y1, y2, y3};
  ((float4*)(outF + base))[tid] = o;
}

// ---------------------------------------------------------------------------
extern "C" void kernel_launch(void* const* d_in, const int* in_sizes, int n_in,
                              void* d_out, int out_size, void* d_ws, size_t ws_size,
                              hipStream_t stream) {
  const float* src    = (const float*)d_in[0];
  const float* Wq     = (const float*)d_in[1];
  const float* bq     = (const float*)d_in[2];
  const float* Wk     = (const float*)d_in[3];
  const float* bk     = (const float*)d_in[4];
  const float* Wv     = (const float*)d_in[5];
  const float* bv     = (const float*)d_in[6];
  const float* Wo     = (const float*)d_in[7];
  const float* bo     = (const float*)d_in[8];
  const float* W1     = (const float*)d_in[9];
  const float* b1     = (const float*)d_in[10];
  const float* W2     = (const float*)d_in[11];
  const float* b2     = (const float*)d_in[12];
  const float* gamma1 = (const float*)d_in[13];
  const float* beta1  = (const float*)d_in[14];
  const float* gamma2 = (const float*)d_in[15];
  const float* beta2  = (const float*)d_in[16];
  float* out = (float*)d_out;
  (void)in_sizes; (void)n_in; (void)out_size;

  char* p = (char*)d_ws;
  size_t used = 0;
  auto carve = [&](size_t n) {
    char* r = p; size_t a = (n + 255) & ~(size_t)255; p += a; used += a; return r;
  };
  unsigned short* srcB  = (unsigned short*)carve((size_t)NTOK * 1024 * 2);   // + attnA reuse
  unsigned short* WqkvT = (unsigned short*)carve((size_t)3072 * 1024 * 2);
  unsigned short* WoT   = (unsigned short*)carve((size_t)1024 * 1024 * 2);
  unsigned short* W1T   = (unsigned short*)carve((size_t)4096 * 1024 * 2);
  unsigned short* W2T   = (unsigned short*)carve((size_t)1024 * 4096 * 2);
  unsigned short* Qb    = (unsigned short*)carve((size_t)NTOK * 1024 * 2);   // \ partial
  unsigned short* Kb    = (unsigned short*)carve((size_t)NTOK * 1024 * 2);   // |  (32MB,
  unsigned short* VTb   = (unsigned short*)carve((size_t)NTOK * 1024 * 2);   // |  2 slices)
  carve((size_t)NTOK * 1024 * 2);                                            // /
  unsigned short* xln   = (unsigned short*)carve((size_t)NTOK * 1024 * 2);
  unsigned short* hmid  = (unsigned short*)carve((size_t)NTOK * 4096 * 2);
  unsigned short* attnA = srcB;             // srcB dead after QKV GEMM
  float* partial2 = (float*)Qb;             // Qb..spare dead after flash (32 MB)
  // dedicated 4-slice partial region if workspace allows
  const size_t need4 = (size_t)NTOK * 1024 * 4 * 4;
  float* partial4 = (ws_size >= used + need4) ? (float*)carve(need4) : nullptr;
  const int nsplit = partial4 ? 4 : 2;
  float* partial = partial4 ? partial4 : partial2;

  // pre-pass (cast + all 6 transposes, one launch)
  TransTab tt;
  tt.src[0] = Wq; tt.src[1] = Wk; tt.src[2] = Wv; tt.src[3] = Wo; tt.src[4] = W1; tt.src[5] = W2;
  tt.dst[0] = WqkvT; tt.dst[1] = WqkvT + 1024 * 1024; tt.dst[2] = WqkvT + 2 * 1024 * 1024;
  tt.dst[3] = WoT; tt.dst[4] = W1T; tt.dst[5] = W2T;
  for (int i = 0; i < 4; ++i) { tt.R[i] = 1024; tt.C[i] = 1024; tt.shift[i] = 5; }
  tt.R[4] = 1024; tt.C[4] = 4096; tt.shift[4] = 7;
  tt.R[5] = 4096; tt.C[5] = 1024; tt.shift[5] = 5;
  tt.start[0] = 0; tt.start[1] = 1024; tt.start[2] = 2048; tt.start[3] = 3072;
  tt.start[4] = 4096; tt.start[5] = 8192;
  tt.cvt_in = src; tt.cvt_out = srcB;
  prep_all<<<16384, 256, 0, stream>>>(tt);

  // QKV projection -> Q(scaled)/K/VT
  gemm_bt<0><<<dim3(24, 32, 1), 256, 0, stream>>>(srcB, WqkvT, NTOK, 3072, 1024, 1024,
                                                  bq, bk, bv, nullptr, nullptr, Qb, Kb, VTb);
  // attention (512 threads, 8 waves — round-4 proven)
  flash_attn<<<dim3(16, 32), 512, 0, stream>>>(Qb, Kb, VTb, attnA);
  // O-projection, split-K -> fp32 partials
  gemm_bt<1><<<dim3(8, 32, nsplit), 256, 0, stream>>>(attnA, WoT, NTOK, 1024, 1024 / nsplit, 1024,
                                                      nullptr, nullptr, nullptr, partial,
                                                      nullptr, nullptr, nullptr, nullptr);
  // LN1 (partials + bo + src residual) -> bf16
  ln_combine1<<<NTOK, 256, 0, stream>>>(partial, nsplit, src, bo, gamma1, beta1, xln);
  // FFN1 + GELU -> bf16
  gemm_bt<2><<<dim3(32, 32, 1), 256, 0, stream>>>(xln, W1T, NTOK, 4096, 1024, 1024,
                                                  b1, nullptr, nullptr, nullptr, hmid,
                                                  nullptr, nullptr, nullptr);
  // FFN2, split-K -> fp32 partials
  gemm_bt<1><<<dim3(8, 32, nsplit), 256, 0, stream>>>(hmid, W2T, NTOK, 1024, 4096 / nsplit, 4096,
                                                      nullptr, nullptr, nullptr, partial,
                                                      nullptr, nullptr, nullptr, nullptr);
  // LN2 (partials + b2 + xln residual) -> f32 out
  ln_combine2<<<NTOK, 256, 0, stream>>>(partial, nsplit, xln, b2, gamma2, beta2, out);
}

// Round 7
// 338.103 us; speedup vs baseline: 1.1591x; 1.0489x over previous
//
#include <hip/hip_runtime.h>
#include <cstdint>
#include <cstddef>

using short8 = short __attribute__((ext_vector_type(8)));   // 8 bf16 = 4 VGPRs
using f32x4  = float __attribute__((ext_vector_type(4)));   // MFMA accumulator

__device__ __forceinline__ unsigned short f2bf(float f) {
  unsigned int u = __float_as_uint(f);
  u += 0x7fffu + ((u >> 16) & 1u);            // round-to-nearest-even
  return (unsigned short)(u >> 16);
}
__device__ __forceinline__ float bf2f(unsigned short s) {
  return __uint_as_float(((unsigned int)s) << 16);
}
// pack two f32 -> two bf16 (round-half-up) in one v_perm_b32
__device__ __forceinline__ unsigned int pack_bf16_rhu(float lo, float hi) {
  unsigned int a = __float_as_uint(lo) + 0x8000u;
  unsigned int b = __float_as_uint(hi) + 0x8000u;
  return __builtin_amdgcn_perm(b, a, 0x07060302u);  // {a.b2,a.b3,b.b2,b.b3}
}
__device__ __forceinline__ void async16(const void* g, void* l) {
  __builtin_amdgcn_global_load_lds(
      (const __attribute__((address_space(1))) unsigned int*)g,
      (__attribute__((address_space(3))) unsigned int*)l, 16, 0, 0);
}

#define D_MODEL 1024
#define NHEAD   16
#define HEADD   64
#define SEQL    2048
#define NTOK    4096
// 0.125 (1/sqrt(64)) * log2(e): folded into Q so softmax uses v_exp_f32 directly
#define QSCALE  0.18033688011112042f

// ---------------------------------------------------------------------------
// prep: blocks [0,4096) cast src f32->bf16; blocks [4096,16384) transpose the
// 6 weight matrices ([R][C] f32 -> [C][R] bf16). One launch total.
// ---------------------------------------------------------------------------
struct TransTab {
  const float* src[6];
  unsigned short* dst[6];
  int R[6], C[6], start[6], shift[6];
  const float* cvt_in;
  unsigned short* cvt_out;
};

__global__ __launch_bounds__(256) void prep_all(TransTab tt) {
  __shared__ float tile[32][33];
  int id = blockIdx.x;
  if (id < 4096) {               // cast path: 4096 blocks x 256 thr x 1 float4
    int i = id * 256 + threadIdx.x;
    float4 v = ((const float4*)tt.cvt_in)[i];
    union { unsigned long long u; unsigned int ui[2]; } pk;
    pk.ui[0] = pack_bf16_rhu(v.x, v.y);
    pk.ui[1] = pack_bf16_rhu(v.z, v.w);
    ((unsigned long long*)tt.cvt_out)[i] = pk.u;
    return;
  }
  id -= 4096;
  int m = 0;
#pragma unroll
  for (int i = 1; i < 6; ++i) if (id >= tt.start[i]) m = i;
  const int local = id - tt.start[m];
  const int R = tt.R[m], C = tt.C[m];
  const int bc = (local & ((1 << tt.shift[m]) - 1)) * 32;
  const int br = (local >> tt.shift[m]) * 32;
  const float* in = tt.src[m];
  unsigned short* out = tt.dst[m];
  const int tx = threadIdx.x & 31, ty = threadIdx.x >> 5;
#pragma unroll
  for (int i = 0; i < 32; i += 8)
    tile[ty + i][tx] = in[(size_t)(br + ty + i) * C + bc + tx];
  __syncthreads();
#pragma unroll
  for (int i = 0; i < 32; i += 8)
    out[(size_t)(bc + ty + i) * R + br + tx] = f2bf(tile[tx][ty + i]);
}

// ---------------------------------------------------------------------------
// GEMM: C[M][N] = A[M][K-slice] @ B^T, B stored [N][Kstride].
// blockIdx.z selects K-slice. 128x128 tile, BK=64, 4 waves.
// MODE 0: QKV  (+bias, scatter Q*QSCALE / K / V^T)
// MODE 1: PARTIAL (raw fp32 -> outF + z*M*N)
// MODE 2: FFN1 (+bias, tanh-approx GELU -> bf16)
// ---------------------------------------------------------------------------
template <int MODE>
__global__ __launch_bounds__(256, 4)
void gemm_bt(const unsigned short* __restrict__ A, const unsigned short* __restrict__ B,
             int M, int N, int K, int Kstride,
             const float* __restrict__ bias0, const float* __restrict__ bias1,
             const float* __restrict__ bias2,
             float* __restrict__ outF, unsigned short* __restrict__ outB,
             unsigned short* __restrict__ outQ, unsigned short* __restrict__ outK,
             unsigned short* __restrict__ outVT) {
  __shared__ __align__(16) short sA[128 * 64];   // 16 KB
  __shared__ __align__(16) short sB[128 * 64];   // 16 KB
  const int tid = threadIdx.x, wave = tid >> 6, lane = tid & 63;
  const int quad = lane >> 4, l16 = lane & 15;
  const int bm = blockIdx.y * 128, bn = blockIdx.x * 128;
  const int koff = blockIdx.z * K;
  const int wr = (wave >> 1) * 64, wc = (wave & 1) * 64;
  const f32x4 zero4 = {0.f, 0.f, 0.f, 0.f};
  f32x4 acc[4][4];
#pragma unroll
  for (int i = 0; i < 4; ++i)
#pragma unroll
    for (int j = 0; j < 4; ++j) acc[i][j] = zero4;

  for (int kt = 0; kt < K; kt += 64) {
    __syncthreads();
#pragma unroll
    for (int j = 0; j < 4; ++j) {
      int c = (wave * 4 + j) * 64 + lane;       // chunk 0..1023
      int row = c >> 3, cp = c & 7;
      int gk = koff + kt + ((cp ^ (row & 7)) * 8);
      async16(A + (size_t)(bm + row) * Kstride + gk, &sA[(wave * 4 + j) * 512]);
      async16(B + (size_t)(bn + row) * Kstride + gk, &sB[(wave * 4 + j) * 512]);
    }
    __syncthreads();
#pragma unroll
    for (int kk = 0; kk < 2; ++kk) {            // two 32-k half-steps
      short8 af[4], bfr[4];
#pragma unroll
      for (int i = 0; i < 4; ++i) {
        int ra = wr + i * 16 + l16;
        af[i] = *(const short8*)&sA[ra * 64 + (((kk * 4 + quad) ^ (ra & 7)) * 8)];
        int rb = wc + i * 16 + l16;
        bfr[i] = *(const short8*)&sB[rb * 64 + (((kk * 4 + quad) ^ (rb & 7)) * 8)];
      }
#pragma unroll
      for (int mi = 0; mi < 4; ++mi)
#pragma unroll
        for (int ni = 0; ni < 4; ++ni)
          acc[mi][ni] = __builtin_amdgcn_mfma_f32_16x16x32_bf16(af[mi], bfr[ni], acc[mi][ni], 0, 0, 0);
    }
  }

#pragma unroll
  for (int mi = 0; mi < 4; ++mi)
#pragma unroll
    for (int ni = 0; ni < 4; ++ni) {
      const int col = bn + wc + ni * 16 + l16;
      const int row0 = bm + wr + mi * 16 + quad * 4;
      if constexpr (MODE == 0) {
        const int b_ = row0 >> 11, l_ = row0 & 2047;   // 4 rows never straddle batch
        if (col < 1024) {
          const int hh = col >> 6, dd = col & 63;
          const size_t o = (((size_t)(b_ * NHEAD + hh)) * SEQL + l_) * HEADD + dd;
#pragma unroll
          for (int r = 0; r < 4; ++r)
            outQ[o + (size_t)r * HEADD] = f2bf((acc[mi][ni][r] + bias0[col]) * QSCALE);
        } else if (col < 2048) {
          const int n2 = col - 1024, hh = n2 >> 6, dd = n2 & 63;
          const size_t o = (((size_t)(b_ * NHEAD + hh)) * SEQL + l_) * HEADD + dd;
#pragma unroll
          for (int r = 0; r < 4; ++r)
            outK[o + (size_t)r * HEADD] = f2bf(acc[mi][ni][r] + bias1[n2]);
        } else {
          const int n2 = col - 2048, hh = n2 >> 6, dd = n2 & 63;
          union { unsigned long long u; unsigned short us[4]; } pk;
#pragma unroll
          for (int r = 0; r < 4; ++r) pk.us[r] = f2bf(acc[mi][ni][r] + bias2[n2]);
          *(unsigned long long*)&outVT[(((size_t)(b_ * NHEAD + hh)) * HEADD + dd) * SEQL + l_] = pk.u;
        }
      } else if constexpr (MODE == 1) {
        float* o = outF + (size_t)blockIdx.z * M * N + (size_t)row0 * N + col;
#pragma unroll
        for (int r = 0; r < 4; ++r) o[(size_t)r * N] = acc[mi][ni][r];
      } else {
#pragma unroll
        for (int r = 0; r < 4; ++r) {
          float x = acc[mi][ni][r] + bias0[col];
          float x2 = x * x;
          float z = x * fmaf(0.102944f, x2, 2.302208f);
          float t = __builtin_amdgcn_exp2f(z);
          float gl = x - x * __builtin_amdgcn_rcpf(t + 1.0f);
          outB[(size_t)(row0 + r) * N + col] = f2bf(gl);
        }
      }
    }
}

// ---------------------------------------------------------------------------
// Flash attention: 512 threads = 4 q-groups (wq) x 2 kv-halves (wk).
// Each wave owns 32 q x 64 kv per 128-kv tile: every K-frag and V-frag feeds
// 2 MFMAs (mi reuse) -> ~24 KB LDS/wave/tile for 32 MFMAs (round-4: ~40 KB).
// S^T = K.Q^T (P lands q on lane&15, kv on quad*4+r: b64 P writes, direct
// A-frag reads, wave-private). O/lsum partial per kv-half; one cross-wave
// LDS reduction at block end (reuses dead sP). No max-subtraction (scores
// bounded; softmax shift-invariant). LDS ~68.5 KB -> 2 blocks/CU = 16 waves.
// ---------------------------------------------------------------------------
__global__ __launch_bounds__(512, 4)
void flash_attn(const unsigned short* __restrict__ Qb, const unsigned short* __restrict__ Kb,
                const unsigned short* __restrict__ VTb, unsigned short* __restrict__ attnA) {
  __shared__ __align__(16) short sK[128 * 64];    // [kv][d] swizzled (Q staging first)
  __shared__ __align__(16) short sV[64 * 128];    // [d][kv] swizzled
  __shared__ __align__(16) short sP[8 * 32 * 72]; // per-wave 32q x (64kv + pad)
  __shared__ float lred[4][32];                   // wk=1 lsum dump
  const int tid = threadIdx.x, wave = tid >> 6, lane = tid & 63;
  const int quad = lane >> 4, l16 = lane & 15;
  const int wq = wave >> 1;        // 0..3: q-group (32 rows)
  const int wk = wave & 1;         // 0..1: kv half
  const int bh = blockIdx.y;
  const int q0 = blockIdx.x * 128;
  const size_t baseQK = (size_t)bh * SEQL * HEADD;
  const size_t baseV  = (size_t)bh * HEADD * SEQL;
  const int pbase = wave * (32 * 72);

  // stage Q tile (128x64) into sK, lift B-fragments to registers
#pragma unroll
  for (int j = 0; j < 2; ++j) {
    int c = (wave * 2 + j) * 64 + lane;
    int row = c >> 3, cp = c & 7;
    int gk = (cp ^ (row & 7)) * 8;
    async16(Qb + baseQK + (size_t)(q0 + row) * HEADD + gk, &sK[(wave * 2 + j) * 512]);
  }
  __syncthreads();
  short8 qf[2][2];
#pragma unroll
  for (int mi = 0; mi < 2; ++mi)
#pragma unroll
    for (int kk = 0; kk < 2; ++kk) {
      int m = wq * 32 + mi * 16 + l16;
      qf[mi][kk] = *(const short8*)&sK[m * 64 + (((kk * 4 + quad) ^ (m & 7)) * 8)];
    }

  const f32x4 zero4 = {0.f, 0.f, 0.f, 0.f};
  f32x4 o_acc[2][4];                 // [mi][d-tile]; row=q(quad*4+r), col=d(l16)
  float lsum[2] = {0.f, 0.f};        // partial (this kv half) for q = wq*32+mi*16+l16
#pragma unroll
  for (int mi = 0; mi < 2; ++mi)
#pragma unroll
    for (int ni = 0; ni < 4; ++ni) o_acc[mi][ni] = zero4;

  for (int t0 = 0; t0 < SEQL; t0 += 128) {
    __syncthreads();               // all reads of sK/sV (or Q-frags) done
#pragma unroll
    for (int j = 0; j < 2; ++j) {
      int c = (wave * 2 + j) * 64 + lane;
      { int row = c >> 3, cp = c & 7;
        int gk = (cp ^ (row & 7)) * 8;
        async16(Kb + baseQK + (size_t)(t0 + row) * HEADD + gk, &sK[(wave * 2 + j) * 512]); }
      { int d = c >> 4, cp = c & 15;
        int gl = (cp ^ (d & 15)) * 8;
        async16(VTb + baseV + (size_t)d * SEQL + t0 + gl, &sV[(wave * 2 + j) * 512]); }
    }
    __syncthreads();

    // ---- S^T[kv][q] for this wave's 64-kv half: A = K rows, B = Q regs ----
    f32x4 st[4][2];
#pragma unroll
    for (int kt = 0; kt < 4; ++kt)
#pragma unroll
      for (int mi = 0; mi < 2; ++mi) st[kt][mi] = zero4;
#pragma unroll
    for (int kt = 0; kt < 4; ++kt) {
      int krow = wk * 64 + kt * 16 + l16;
      short8 a0 = *(const short8*)&sK[krow * 64 + ((quad ^ (krow & 7)) * 8)];
      short8 a1 = *(const short8*)&sK[krow * 64 + (((4 + quad) ^ (krow & 7)) * 8)];
#pragma unroll
      for (int mi = 0; mi < 2; ++mi) {
        st[kt][mi] = __builtin_amdgcn_mfma_f32_16x16x32_bf16(a0, qf[mi][0], st[kt][mi], 0, 0, 0);
        st[kt][mi] = __builtin_amdgcn_mfma_f32_16x16x32_bf16(a1, qf[mi][1], st[kt][mi], 0, 0, 0);
      }
    }
    // ---- exp2 (scale pre-folded), accumulate denom, b64 P writes ----
#pragma unroll
    for (int kt = 0; kt < 4; ++kt)
#pragma unroll
      for (int mi = 0; mi < 2; ++mi) {
        float e0 = __builtin_amdgcn_exp2f(st[kt][mi][0]);
        float e1 = __builtin_amdgcn_exp2f(st[kt][mi][1]);
        float e2 = __builtin_amdgcn_exp2f(st[kt][mi][2]);
        float e3 = __builtin_amdgcn_exp2f(st[kt][mi][3]);
        lsum[mi] += (e0 + e1) + (e2 + e3);
        union { unsigned long long u; unsigned int ui[2]; } pk;
        pk.ui[0] = pack_bf16_rhu(e0, e1);
        pk.ui[1] = pack_bf16_rhu(e2, e3);
        *(unsigned long long*)&sP[pbase + (mi * 16 + l16) * 72 + kt * 16 + quad * 4] = pk.u;
      }
    // ---- O += P V over this kv half (sP wave-private; same-wave order ok) ----
#pragma unroll
    for (int c = 0; c < 2; ++c) {
      short8 vf[4];
#pragma unroll
      for (int ni = 0; ni < 4; ++ni) {
        int vrow = ni * 16 + l16;
        vf[ni] = *(const short8*)&sV[vrow * 128 + (((wk * 8 + c * 4 + quad) ^ (vrow & 15)) * 8)];
      }
#pragma unroll
      for (int mi = 0; mi < 2; ++mi) {
        short8 pf = *(const short8*)&sP[pbase + (mi * 16 + l16) * 72 + c * 32 + quad * 8];
#pragma unroll
        for (int ni = 0; ni < 4; ++ni)
          o_acc[mi][ni] = __builtin_amdgcn_mfma_f32_16x16x32_bf16(pf, vf[ni], o_acc[mi][ni], 0, 0, 0);
      }
    }
  }

  // ---- cross-wave reduction: combine kv halves ----
  // reduce partial denominators across quads (same l16 = same q)
#pragma unroll
  for (int mi = 0; mi < 2; ++mi) {
    lsum[mi] += __shfl_xor(lsum[mi], 16, 64);
    lsum[mi] += __shfl_xor(lsum[mi], 32, 64);
  }
  __syncthreads();                 // all sP P-reads done; safe to overwrite
  float* op = (float*)sP;          // [wq][d=64][q-local stride 36] f32 (36.9KB)
  if (wk == 1) {
    float* dst = op + wq * (64 * 36);
#pragma unroll
    for (int mi = 0; mi < 2; ++mi)
#pragma unroll
      for (int ni = 0; ni < 4; ++ni)
        *(f32x4*)&dst[(ni * 16 + l16) * 36 + mi * 16 + quad * 4] = o_acc[mi][ni];
    if (quad == 0) {
      lred[wq][l16] = lsum[0];
      lred[wq][16 + l16] = lsum[1];
    }
  }
  __syncthreads();
  if (wk == 0) {
    const float* srcp = op + wq * (64 * 36);
    const int b_ = bh >> 4, hh = bh & 15;
#pragma unroll
    for (int mi = 0; mi < 2; ++mi) {
      float ltot = lsum[mi] + lred[wq][mi * 16 + l16];  // total denom for q=wq*32+mi*16+l16
#pragma unroll
      for (int ni = 0; ni < 4; ++ni) {
        f32x4 other = *(const f32x4*)&srcp[(ni * 16 + l16) * 36 + mi * 16 + quad * 4];
        o_acc[mi][ni] += other;
      }
#pragma unroll
      for (int r = 0; r < 4; ++r) {
        float inv = 1.0f / __shfl(ltot, quad * 4 + r, 64);
        int qrow = q0 + wq * 32 + mi * 16 + quad * 4 + r;
        size_t orow = ((size_t)(b_ * SEQL + qrow)) * D_MODEL + hh * HEADD;
#pragma unroll
        for (int ni = 0; ni < 4; ++ni)
          attnA[orow + ni * 16 + l16] = f2bf(o_acc[mi][ni][r] * inv);
      }
    }
  }
}

// ---------------------------------------------------------------------------
// LN combine: sum nsplit fp32 partial slices (+bias +residual), LayerNorm.
// ---------------------------------------------------------------------------
__device__ __forceinline__ void ln_core(float x0, float x1, float x2, float x3,
                                        const float* gamma, const float* beta,
                                        int tid, float& y0, float& y1, float& y2, float& y3) {
  float s = x0 + x1 + x2 + x3;
  float q = x0 * x0 + x1 * x1 + x2 * x2 + x3 * x3;
#pragma unroll
  for (int m = 1; m < 64; m <<= 1) {
    s += __shfl_xor(s, m, 64);
    q += __shfl_xor(q, m, 64);
  }
  __shared__ float red[8];
  const int wv = tid >> 6, ln = tid & 63;
  if (ln == 0) { red[wv] = s; red[4 + wv] = q; }
  __syncthreads();
  float S = red[0] + red[1] + red[2] + red[3];
  float Q2 = red[4] + red[5] + red[6] + red[7];
  float mu = S * (1.0f / 1024.0f);
  float var = Q2 * (1.0f / 1024.0f) - mu * mu;
  float rstd = rsqrtf(var + 1e-5f);
  float4 g = ((const float4*)gamma)[tid];
  float4 b = ((const float4*)beta)[tid];
  y0 = (x0 - mu) * rstd * g.x + b.x;
  y1 = (x1 - mu) * rstd * g.y + b.y;
  y2 = (x2 - mu) * rstd * g.z + b.z;
  y3 = (x3 - mu) * rstd * g.w + b.w;
}

__global__ __launch_bounds__(256)
void ln_combine1(const float* __restrict__ p, const float* __restrict__ src,
                 const float* __restrict__ bias, const float* __restrict__ gamma,
                 const float* __restrict__ beta, unsigned short* __restrict__ outB) {
  const int t = blockIdx.x, tid = threadIdx.x;
  const size_t MN = (size_t)NTOK * 1024, base = (size_t)t * 1024;
  float4 a = ((const float4*)(p + base))[tid];
  float4 b4 = ((const float4*)(p + MN + base))[tid];
  a.x += b4.x; a.y += b4.y; a.z += b4.z; a.w += b4.w;
  float4 s4 = ((const float4*)(src + base))[tid];
  float4 bi = ((const float4*)bias)[tid];
  float y0, y1, y2, y3;
  ln_core(a.x + s4.x + bi.x, a.y + s4.y + bi.y,
          a.z + s4.z + bi.z, a.w + s4.w + bi.w,
          gamma, beta, tid, y0, y1, y2, y3);
  union { unsigned long long u; unsigned int ui[2]; } pk;
  pk.ui[0] = (unsigned)f2bf(y0) | ((unsigned)f2bf(y1) << 16);
  pk.ui[1] = (unsigned)f2bf(y2) | ((unsigned)f2bf(y3) << 16);
  ((unsigned long long*)(outB + base))[tid] = pk.u;
}

__global__ __launch_bounds__(256)
void ln_combine2(const float* __restrict__ p, const unsigned short* __restrict__ resB,
                 const float* __restrict__ bias, const float* __restrict__ gamma,
                 const float* __restrict__ beta, float* __restrict__ outF) {
  const int t = blockIdx.x, tid = threadIdx.x;
  const size_t MN = (size_t)NTOK * 1024, base = (size_t)t * 1024;
  float4 a = ((const float4*)(p + base))[tid];
  float4 b4 = ((const float4*)(p + MN + base))[tid];
  a.x += b4.x; a.y += b4.y; a.z += b4.z; a.w += b4.w;
  union { unsigned long long u; unsigned short us[4]; } r;
  r.u = ((const unsigned long long*)(resB + base))[tid];
  float4 bi = ((const float4*)bias)[tid];
  float y0, y1, y2, y3;
  ln_core(a.x + bf2f(r.us[0]) + bi.x, a.y + bf2f(r.us[1]) + bi.y,
          a.z + bf2f(r.us[2]) + bi.z, a.w + bf2f(r.us[3]) + bi.w,
          gamma, beta, tid, y0, y1, y2, y3);
  float4 o = {y0, y1, y2, y3};
  ((float4*)(outF + base))[tid] = o;
}

// ---------------------------------------------------------------------------
extern "C" void kernel_launch(void* const* d_in, const int* in_sizes, int n_in,
                              void* d_out, int out_size, void* d_ws, size_t ws_size,
                              hipStream_t stream) {
  const float* src    = (const float*)d_in[0];
  const float* Wq     = (const float*)d_in[1];
  const float* bq     = (const float*)d_in[2];
  const float* Wk     = (const float*)d_in[3];
  const float* bk     = (const float*)d_in[4];
  const float* Wv     = (const float*)d_in[5];
  const float* bv     = (const float*)d_in[6];
  const float* Wo     = (const float*)d_in[7];
  const float* bo     = (const float*)d_in[8];
  const float* W1     = (const float*)d_in[9];
  const float* b1     = (const float*)d_in[10];
  const float* W2     = (const float*)d_in[11];
  const float* b2     = (const float*)d_in[12];
  const float* gamma1 = (const float*)d_in[13];
  const float* beta1  = (const float*)d_in[14];
  const float* gamma2 = (const float*)d_in[15];
  const float* beta2  = (const float*)d_in[16];
  float* out = (float*)d_out;
  (void)in_sizes; (void)n_in; (void)out_size; (void)ws_size;

  char* p = (char*)d_ws;
  auto carve = [&](size_t n) { char* r = p; p += (n + 255) & ~(size_t)255; return r; };
  unsigned short* srcB  = (unsigned short*)carve((size_t)NTOK * 1024 * 2);   // + attnA reuse
  unsigned short* WqkvT = (unsigned short*)carve((size_t)3072 * 1024 * 2);
  unsigned short* WoT   = (unsigned short*)carve((size_t)1024 * 1024 * 2);
  unsigned short* W1T   = (unsigned short*)carve((size_t)4096 * 1024 * 2);
  unsigned short* W2T   = (unsigned short*)carve((size_t)1024 * 4096 * 2);
  unsigned short* Qb    = (unsigned short*)carve((size_t)NTOK * 1024 * 2);   // \ partial
  unsigned short* Kb    = (unsigned short*)carve((size_t)NTOK * 1024 * 2);   // |  (32MB,
  unsigned short* VTb   = (unsigned short*)carve((size_t)NTOK * 1024 * 2);   // |  2 slices)
  carve((size_t)NTOK * 1024 * 2);                                            // /
  unsigned short* xln   = (unsigned short*)carve((size_t)NTOK * 1024 * 2);
  unsigned short* hmid  = (unsigned short*)carve((size_t)NTOK * 4096 * 2);
  unsigned short* attnA = srcB;             // srcB dead after QKV GEMM
  float* partial = (float*)Qb;              // Qb..spare dead after flash (32 MB)

  // pre-pass (cast + all 6 transposes, one launch)
  TransTab tt;
  tt.src[0] = Wq; tt.src[1] = Wk; tt.src[2] = Wv; tt.src[3] = Wo; tt.src[4] = W1; tt.src[5] = W2;
  tt.dst[0] = WqkvT; tt.dst[1] = WqkvT + 1024 * 1024; tt.dst[2] = WqkvT + 2 * 1024 * 1024;
  tt.dst[3] = WoT; tt.dst[4] = W1T; tt.dst[5] = W2T;
  for (int i = 0; i < 4; ++i) { tt.R[i] = 1024; tt.C[i] = 1024; tt.shift[i] = 5; }
  tt.R[4] = 1024; tt.C[4] = 4096; tt.shift[4] = 7;
  tt.R[5] = 4096; tt.C[5] = 1024; tt.shift[5] = 5;
  tt.start[0] = 0; tt.start[1] = 1024; tt.start[2] = 2048; tt.start[3] = 3072;
  tt.start[4] = 4096; tt.start[5] = 8192;
  tt.cvt_in = src; tt.cvt_out = srcB;
  prep_all<<<16384, 256, 0, stream>>>(tt);

  // QKV projection -> Q(scaled)/K/VT
  gemm_bt<0><<<dim3(24, 32, 1), 256, 0, stream>>>(srcB, WqkvT, NTOK, 3072, 1024, 1024,
                                                  bq, bk, bv, nullptr, nullptr, Qb, Kb, VTb);
  // attention (512 threads: 4 q-groups x 2 kv-halves)
  flash_attn<<<dim3(16, 32), 512, 0, stream>>>(Qb, Kb, VTb, attnA);
  // O-projection, split-K=2 -> fp32 partials
  gemm_bt<1><<<dim3(8, 32, 2), 256, 0, stream>>>(attnA, WoT, NTOK, 1024, 512, 1024,
                                                 nullptr, nullptr, nullptr, partial,
                                                 nullptr, nullptr, nullptr, nullptr);
  // LN1 (partials + bo + src residual) -> bf16
  ln_combine1<<<NTOK, 256, 0, stream>>>(partial, src, bo, gamma1, beta1, xln);
  // FFN1 + GELU -> bf16
  gemm_bt<2><<<dim3(32, 32, 1), 256, 0, stream>>>(xln, W1T, NTOK, 4096, 1024, 1024,
                                                  b1, nullptr, nullptr, nullptr, hmid,
                                                  nullptr, nullptr, nullptr);
  // FFN2, split-K=2 -> fp32 partials
  gemm_bt<1><<<dim3(8, 32, 2), 256, 0, stream>>>(hmid, W2T, NTOK, 1024, 2048, 4096,
                                                 nullptr, nullptr, nullptr, partial,
                                                 nullptr, nullptr, nullptr, nullptr);
  // LN2 (partials + b2 + xln residual) -> f32 out
  ln_combine2<<<NTOK, 256, 0, stream>>>(partial, xln, b2, gamma2, beta2, out);
}